// Round 7
// baseline (1072.563 us; speedup 1.0000x reference)
//
#include <hip/hip_runtime.h>

// ---------------------------------------------------------------------------
// TransformerAgent (Performer/FAVOR+ encoder), MI355X gfx950.
// Round 21: r19 (best, 1001.6us) + coalesced-store epilogue in gemm_pipe2.
// r20 fusion REVERTED (110us vs 84us split; phase-2 vmcnt(0) serialization).
// Diagnosis: write-heavy GEMMs (QKV 100MB, FF1 131MB) plateau at ~2.2 TB/s
// write BW across 4 different schedules -> the scalar 2-byte C-stores
// (4 rows x 32B segments per wave store) are the common bottleneck, not the
// MFMA schedule. Fix: stage C half-tiles through the dead LDS ring (64 KB,
// total 160 KB) and flush with 16B/lane global_store_dwordx4 (512-B wave
// segments). Math/staging/LN kernels byte-identical to r19.
// B=16, L=4096(=1+4095), HID=256, NH=8, DH=32, FF=1024, NL=4, ACT=32
// ---------------------------------------------------------------------------

typedef unsigned short bf16_t;
typedef __attribute__((ext_vector_type(8))) short short8;
typedef __attribute__((ext_vector_type(4))) float float4v;

#define NB 16
#define LSEQ 4096
#define MROWS (NB * LSEQ)      // 65536
#define HIDD 256
#define NHEAD 8
#define DHEAD 32
#define FFD 1024
#define NLAY 4
#define KEPS_F 1e-3f
#define LNEPS_F 1e-6f
#define KV_ELEMS (NB * NHEAD * 32 * 33)   // 135168

__device__ __forceinline__ float b2f(bf16_t h) {
    return __uint_as_float(((unsigned int)h) << 16);
}
__device__ __forceinline__ bf16_t f2b(float f) {
    unsigned int u = __float_as_uint(f);
    u += 0x7fffu + ((u >> 16) & 1u);   // round-to-nearest-even
    return (bf16_t)(u >> 16);
}

// async global->LDS, 16B per lane
#define GLOAD_LDS16(g, l)                                                     \
    __builtin_amdgcn_global_load_lds(                                         \
        (const __attribute__((address_space(1))) void*)(g),                   \
        (__attribute__((address_space(3))) void*)(l), 16, 0, 0)

// raw barrier (no compiler-forced vmcnt(0) drain, unlike __syncthreads)
#define SBAR() __builtin_amdgcn_s_barrier()
#define WAITV(n)                                                              \
    do {                                                                      \
        asm volatile("s_waitcnt vmcnt(" #n ")" ::: "memory");                 \
        __builtin_amdgcn_sched_barrier(0);                                    \
    } while (0)

// LDS fragment read: (row R, k-chunk quad) of a [256]x32 panel stored in
// pair-row-XOR-swizzled chunk order (matches stage swizzle below).
#define FRAG16(L, R)                                                          \
    (*(const short8*)&(L)[((((R) >> 1) * 8) +                                  \
        (((((R) & 1) << 2) | quad) ^ (((R) >> 1) & 7))) * 8])

// ---------------------------------------------------------------------------
// Convert+transpose: in[z*ils + R][C] f32 -> out[z*ols + C][R] bf16.
// ---------------------------------------------------------------------------
__global__ __launch_bounds__(256) void conv_transpose_kernel(
    const float* __restrict__ in, bf16_t* __restrict__ out, int R, int C,
    size_t ils, size_t ols)
{
    __shared__ float tile[32][33];
    const size_t ib = (size_t)blockIdx.z * ils;
    const size_t ob = (size_t)blockIdx.z * ols;
    const int r0 = blockIdx.y * 32, c0 = blockIdx.x * 32;
    const int tx = threadIdx.x & 31, ty = threadIdx.x >> 5;   // 32 x 8
#pragma unroll
    for (int rr = ty; rr < 32; rr += 8)
        tile[rr][tx] = in[ib + (size_t)(r0 + rr) * C + c0 + tx];
    __syncthreads();
#pragma unroll
    for (int rr = ty; rr < 32; rr += 8)
        out[ob + (size_t)(c0 + rr) * R + r0 + tx] = f2b(tile[tx][rr]);
}

// concat per-layer q/k/v biases into bqkv[l][768]
__global__ __launch_bounds__(256) void concat_bias_kernel(
    const float* __restrict__ bq, const float* __restrict__ bk,
    const float* __restrict__ bv, float* __restrict__ bqkv)
{
    const int l = blockIdx.x, j = threadIdx.x;
    bqkv[l * 768 + j]       = bq[l * 256 + j];
    bqkv[l * 768 + 256 + j] = bk[l * 256 + j];
    bqkv[l * 768 + 512 + j] = bv[l * 256 + j];
}

// ---------------------------------------------------------------------------
// Embed A-prep: Ain[b*4096+l][128] = (l==0) ? 0 : bf16(ins[b][l-1][:])
// ---------------------------------------------------------------------------
__global__ __launch_bounds__(256) void prep_a_kernel(
    const float* __restrict__ ins, bf16_t* __restrict__ Ain)
{
    const int row = blockIdx.x * 2 + (threadIdx.x >> 7);
    const int j = threadIdx.x & 127;
    const int b = row >> 12, l = row & (LSEQ - 1);
    bf16_t v = 0;
    if (l != 0) v = f2b(ins[((size_t)b * 4095 + (l - 1)) * 128 + j]);
    Ain[(size_t)row * 128 + j] = v;
}

// X[b,0,:] = resets ? 0 : hidden
__global__ __launch_bounds__(256) void fix_row0_kernel(
    const float* __restrict__ hidden, const int* __restrict__ resets,
    bf16_t* __restrict__ X)
{
    const int b = blockIdx.x, j = threadIdx.x;
    float v = resets[b] ? 0.f : hidden[b * HIDD + j];
    X[((size_t)b * LSEQ) * HIDD + j] = f2b(v);
}

// ---------------------------------------------------------------------------
// Pipelined MFMA GEMM v2 + coalesced-store epilogue.
// 256x256 block, 8 waves 2m x 4n (wave 128x64), BK=32, 3-slot ring.
// Epilogue: stage C half-tiles (128x256 bf16 = 64 KB) through dead-ring LDS,
// flush with 16B/lane dwordx4 stores (512-B segments).
// Requires M%256==0, (M/256)%8==0, N%256==0, K%32==0, KT>=4.
// ---------------------------------------------------------------------------
template <int MODE>
__global__ __launch_bounds__(512, 2) void gemm_pipe2(
    const bf16_t* __restrict__ A, const bf16_t* __restrict__ WT,
    const float* __restrict__ bias, bf16_t* __restrict__ C,
    int M, int N, int K, int lda, int ldc)
{
    __shared__ __align__(16) char smem[163840];        // 160 KB exactly
    bf16_t* AsP = (bf16_t*)smem;                       // 3 x 8192 elems (48 KB)
    bf16_t* BsP = (bf16_t*)(smem + 49152);             // 3 x 8192 elems (48 KB)
    bf16_t* Cs  = (bf16_t*)(smem + 98304);             // 128x256 bf16 (64 KB)

    const int tid = threadIdx.x;
    const int wave = tid >> 6, lane = tid & 63;
    const int quad = lane >> 4, mr = lane & 15;

    // XCD-aware decode (BM=256)
    const int Nn = N >> 8;
    const int id = blockIdx.x;
    const int s = id >> 3;
    const int bm = (((id & 7) + ((s / Nn) << 3))) << 8;   // *256
    const int bn = (s % Nn) << 8;                         // *256

    const int wm = (wave & 1) << 7;     // 0 / 128
    const int wn = (wave >> 1) << 6;    // 0 / 64 / 128 / 192

    const int KT = K >> 5;              // # of 32-wide K-tiles

    float bcol[4];
#pragma unroll
    for (int j = 0; j < 4; ++j) bcol[j] = bias[bn + wn + j * 16 + mr];
    asm volatile("s_waitcnt vmcnt(0)" ::: "memory");
    __builtin_amdgcn_sched_barrier(0);

    auto stageA = [&](int t) {
        const int k0 = t << 5;
        bf16_t* L = AsP + (t % 3) * 8192;
#pragma unroll
        for (int it = 0; it < 2; ++it) {
            const int c = it * 512 + tid;
            const int r = c >> 2;
            const int up = ((((r & 1) << 2) | (c & 3)) ^ ((r >> 1) & 7));
            const int grow = ((r >> 1) << 1) | (up >> 2);
            GLOAD_LDS16(A + (size_t)(bm + grow) * lda + k0 + ((up & 3) << 3),
                        L + c * 8);
        }
    };
    auto stageB = [&](int t) {
        const int k0 = t << 5;
        bf16_t* L = BsP + (t % 3) * 8192;
#pragma unroll
        for (int it = 0; it < 2; ++it) {
            const int c = it * 512 + tid;
            const int r = c >> 2;
            const int up = ((((r & 1) << 2) | (c & 3)) ^ ((r >> 1) & 7));
            const int grow = ((r >> 1) << 1) | (up >> 2);
            GLOAD_LDS16(WT + (size_t)(bn + grow) * K + k0 + ((up & 3) << 3),
                        L + c * 8);
        }
    };

    float4v acc[8][4];
#pragma unroll
    for (int i = 0; i < 8; i++)
#pragma unroll
        for (int j = 0; j < 4; j++) acc[i][j] = (float4v)(0.f);

    const int P = KT < 2 ? KT : 2;
    for (int tt = 0; tt < P; ++tt) { stageA(tt); stageB(tt); }

    for (int t = 0; t < KT; ++t) {
        if (t < KT - 1) { WAITV(4); } else { WAITV(0); }
        SBAR();
        __builtin_amdgcn_sched_barrier(0);
        const bf16_t* LA = AsP + (t % 3) * 8192;
        const bf16_t* LB = BsP + (t % 3) * 8192;
        short8 a0[4], a1[4], b[4];
#pragma unroll
        for (int j = 0; j < 4; ++j) b[j]  = FRAG16(LB, wn + j * 16 + mr);
#pragma unroll
        for (int i = 0; i < 4; ++i) a0[i] = FRAG16(LA, wm + i * 16 + mr);
#pragma unroll
        for (int i = 0; i < 4; ++i) a1[i] = FRAG16(LA, wm + 64 + i * 16 + mr);
        if (t + 2 < KT) { stageA(t + 2); stageB(t + 2); }
        __builtin_amdgcn_s_setprio(1);
        __builtin_amdgcn_sched_barrier(0);
#pragma unroll
        for (int i = 0; i < 4; ++i)
#pragma unroll
            for (int j = 0; j < 4; ++j)
                acc[i][j] = __builtin_amdgcn_mfma_f32_16x16x32_bf16(
                    a0[i], b[j], acc[i][j], 0, 0, 0);
#pragma unroll
        for (int i = 0; i < 4; ++i)
#pragma unroll
            for (int j = 0; j < 4; ++j)
                acc[4 + i][j] = __builtin_amdgcn_mfma_f32_16x16x32_bf16(
                    a1[i], b[j], acc[4 + i][j], 0, 0, 0);
        __builtin_amdgcn_sched_barrier(0);
        __builtin_amdgcn_s_setprio(0);
    }

    // ---- coalesced-store epilogue: stage C half-tiles through LDS ----
    __syncthreads();                                   // ring fully dead
#pragma unroll
    for (int h = 0; h < 2; ++h) {
        if ((wave & 1) == h) {                         // owning-parity waves
#pragma unroll
            for (int i = 0; i < 8; ++i) {
#pragma unroll
                for (int r = 0; r < 4; ++r) {
                    const int row = i * 16 + quad * 4 + r;   // 0..127
#pragma unroll
                    for (int j = 0; j < 4; ++j) {
                        float v = acc[i][j][r] + bcol[j];
                        if (MODE == 1) v = fmaxf(v, 0.f);
                        Cs[row * 256 + wn + j * 16 + mr] = f2b(v);
                    }
                }
            }
        }
        __syncthreads();
        // flush: 4096 chunks of 16 B, 512-B contiguous wave segments
#pragma unroll
        for (int it = 0; it < 8; ++it) {
            const int e = it * 512 + tid;
            const int row = e >> 5, c16 = e & 31;
            const short8 v = *(const short8*)&Cs[row * 256 + c16 * 8];
            *(short8*)(C + (size_t)(bm + h * 128 + row) * ldc + bn + c16 * 8) = v;
        }
        __syncthreads();
    }
}

// ---------------------------------------------------------------------------
// v2 core + fused LayerNorm epilogue (FF2/Wo-LN): out = LN(2*(A@W+b))*sc+bi.
// (r19, unchanged) N=256 fixed, 256 rows/block.
// ---------------------------------------------------------------------------
__global__ __launch_bounds__(512, 2) void gemm_pipe2_ln(
    const bf16_t* __restrict__ A, const bf16_t* __restrict__ WT,
    const float* __restrict__ bias, const float* __restrict__ sc,
    const float* __restrict__ bi, bf16_t* __restrict__ out,
    int K, int lda)
{
    __shared__ __align__(16) bf16_t As[3][256 * 32];   // 48 KB
    __shared__ __align__(16) bf16_t Bs[3][256 * 32];   // 48 KB
    __shared__ float red[8][128][2];                   // 8 KB
    __shared__ float fin[256][2];                      // 2 KB

    const int tid = threadIdx.x;
    const int wave = tid >> 6, lane = tid & 63;
    const int quad = lane >> 4, mr = lane & 15;
    const int bm = blockIdx.x << 8;                    // *256

    const int wm = (wave & 1) << 7;
    const int wn = (wave >> 1) << 6;

    const int KT = K >> 5;

    float bcol[4], scv[4], biv[4];
#pragma unroll
    for (int j = 0; j < 4; ++j) {
        bcol[j] = bias[wn + j * 16 + mr];
        scv[j]  = sc[wn + j * 16 + mr];
        biv[j]  = bi[wn + j * 16 + mr];
    }
    asm volatile("s_waitcnt vmcnt(0)" ::: "memory");
    __builtin_amdgcn_sched_barrier(0);

    auto stageA = [&](int t) {
        const int k0 = t << 5;
        bf16_t* L = &As[t % 3][0];
#pragma unroll
        for (int it = 0; it < 2; ++it) {
            const int c = it * 512 + tid;
            const int r = c >> 2;
            const int up = ((((r & 1) << 2) | (c & 3)) ^ ((r >> 1) & 7));
            const int grow = ((r >> 1) << 1) | (up >> 2);
            GLOAD_LDS16(A + (size_t)(bm + grow) * lda + k0 + ((up & 3) << 3),
                        L + c * 8);
        }
    };
    auto stageB = [&](int t) {
        const int k0 = t << 5;
        bf16_t* L = &Bs[t % 3][0];
#pragma unroll
        for (int it = 0; it < 2; ++it) {
            const int c = it * 512 + tid;
            const int r = c >> 2;
            const int up = ((((r & 1) << 2) | (c & 3)) ^ ((r >> 1) & 7));
            const int grow = ((r >> 1) << 1) | (up >> 2);
            GLOAD_LDS16(WT + (size_t)grow * K + k0 + ((up & 3) << 3),
                        L + c * 8);
        }
    };

    float4v acc[8][4];
#pragma unroll
    for (int i = 0; i < 8; i++)
#pragma unroll
        for (int j = 0; j < 4; j++) acc[i][j] = (float4v)(0.f);

    const int P = KT < 2 ? KT : 2;
    for (int tt = 0; tt < P; ++tt) { stageA(tt); stageB(tt); }

    for (int t = 0; t < KT; ++t) {
        if (t < KT - 1) { WAITV(4); } else { WAITV(0); }
        SBAR();
        __builtin_amdgcn_sched_barrier(0);
        const bf16_t* LA = &As[t % 3][0];
        const bf16_t* LB = &Bs[t % 3][0];
        short8 a0[4], a1[4], b[4];
#pragma unroll
        for (int j = 0; j < 4; ++j) b[j]  = FRAG16(LB, wn + j * 16 + mr);
#pragma unroll
        for (int i = 0; i < 4; ++i) a0[i] = FRAG16(LA, wm + i * 16 + mr);
#pragma unroll
        for (int i = 0; i < 4; ++i) a1[i] = FRAG16(LA, wm + 64 + i * 16 + mr);
        if (t + 2 < KT) { stageA(t + 2); stageB(t + 2); }
        __builtin_amdgcn_s_setprio(1);
        __builtin_amdgcn_sched_barrier(0);
#pragma unroll
        for (int i = 0; i < 4; ++i)
#pragma unroll
            for (int j = 0; j < 4; ++j)
                acc[i][j] = __builtin_amdgcn_mfma_f32_16x16x32_bf16(
                    a0[i], b[j], acc[i][j], 0, 0, 0);
#pragma unroll
        for (int i = 0; i < 4; ++i)
#pragma unroll
            for (int j = 0; j < 4; ++j)
                acc[4 + i][j] = __builtin_amdgcn_mfma_f32_16x16x32_bf16(
                    a1[i], b[j], acc[4 + i][j], 0, 0, 0);
        __builtin_amdgcn_sched_barrier(0);
        __builtin_amdgcn_s_setprio(0);
    }

#pragma unroll
    for (int i = 0; i < 8; ++i) {
#pragma unroll
        for (int r = 0; r < 4; ++r) {
            float ss = 0.f, s2 = 0.f;
#pragma unroll
            for (int j = 0; j < 4; ++j) {
                const float v = 2.0f * (acc[i][j][r] + bcol[j]);
                ss += v; s2 += v * v;
            }
#pragma unroll
            for (int off = 1; off < 16; off <<= 1) {
                ss += __shfl_xor(ss, off, 64);
                s2 += __shfl_xor(s2, off, 64);
            }
            if (mr == 0) {
                const int rl = i * 16 + quad * 4 + r;
                red[wave][rl][0] = ss;
                red[wave][rl][1] = s2;
            }
        }
    }
    __syncthreads();
    {
        const int R = tid >> 1, p = tid & 1;
        const int mh = R >> 7, rl = R & 127;
        fin[R][p] = red[mh][rl][p] + red[mh + 2][rl][p]
                  + red[mh + 4][rl][p] + red[mh + 6][rl][p];
    }
    __syncthreads();

#pragma unroll
    for (int i = 0; i < 8; ++i) {
#pragma unroll
        for (int r = 0; r < 4; ++r) {
            const int R = wm + i * 16 + quad * 4 + r;
            const float mean = fin[R][0] * (1.0f / 256.0f);
            const float var  = fin[R][1] * (1.0f / 256.0f) - mean * mean;
            const float rs = rsqrtf(var + LNEPS_F);
            bf16_t* crow = out + (size_t)(bm + R) * 256 + wn + mr;
#pragma unroll
            for (int j = 0; j < 4; ++j) {
                const float v = 2.0f * (acc[i][j][r] + bcol[j]);
                crow[j * 16] = f2b((v - mean) * rs * scv[j] + biv[j]);
            }
        }
    }
}

// ---------------------------------------------------------------------------
// FAVOR A-gen (standalone, proven): Afav = (qp @ kv) / (qp @ kps).
// ---------------------------------------------------------------------------
__global__ __launch_bounds__(512) void favor_a_kernel(
    const bf16_t* __restrict__ QKV, const float* __restrict__ KV,
    bf16_t* __restrict__ Afav)
{
    __shared__ __align__(16) bf16_t kvT[NHEAD * 34 * 36];   // 19.1 KB

    const int tid = threadIdx.x;
    const int wave = tid >> 6, lane = tid & 63;
    const int bm = blockIdx.x * 128;
    const int b = bm >> 12;
    const int quad = lane >> 4, mr = lane & 15;

    for (int e = tid; e < NHEAD * 34 * 32; e += 512) {
        const int h = e / (34 * 32);
        const int rem = e - h * (34 * 32);
        const int d = rem >> 5, m = rem & 31;
        bf16_t v = 0;
        if (d < 33) v = f2b(KV[((size_t)(b * NHEAD + h)) * (32 * 33) + m * 33 + d]);
        kvT[(h * 34 + d) * 36 + m] = v;
    }
    __syncthreads();

    const int Rrow = bm + wave * 16 + mr;
    const size_t abase = (size_t)(bm + wave * 16) * 256;

    short8 araw[NHEAD];
#pragma unroll
    for (int h = 0; h < NHEAD; ++h)
        araw[h] = *(const short8*)(QKV + (size_t)Rrow * 768 + h * 32 + quad * 8);

#pragma unroll
    for (int h = 0; h < NHEAD; ++h) {
        short8 a;
#pragma unroll
        for (int j = 0; j < 8; j++)
            a[j] = (short)f2b(fmaxf(b2f((bf16_t)araw[h][j]), 0.f) + KEPS_F);
        short8 bf0 = *(const short8*)&kvT[(h * 34 + mr) * 36 + quad * 8];
        short8 bf1 = *(const short8*)&kvT[(h * 34 + 16 + mr) * 36 + quad * 8];
        short8 bden;
#pragma unroll
        for (int j = 0; j < 8; j++) bden[j] = 0;
        if (mr == 0)
            bden = *(const short8*)&kvT[(h * 34 + 32) * 36 + quad * 8];
        float4v c0 = __builtin_amdgcn_mfma_f32_16x16x32_bf16(a, bf0, (float4v)(0.f), 0, 0, 0);
        float4v c1 = __builtin_amdgcn_mfma_f32_16x16x32_bf16(a, bf1, (float4v)(0.f), 0, 0, 0);
        float4v c2 = __builtin_amdgcn_mfma_f32_16x16x32_bf16(a, bden, (float4v)(0.f), 0, 0, 0);
#pragma unroll
        for (int r = 0; r < 4; r++) {
            const float den = __shfl(c2[r], quad << 4);
            const float rinv = 1.0f / den;
            const int rl = quad * 4 + r;
            Afav[abase + (size_t)rl * 256 + h * 32 + mr]      = f2b(c0[r] * rinv);
            Afav[abase + (size_t)rl * 256 + h * 32 + 16 + mr] = f2b(c1[r] * rinv);
        }
    }
}

// ---------------------------------------------------------------------------
// Zero the KV accumulator
// ---------------------------------------------------------------------------
__global__ __launch_bounds__(256) void zero_kv(float* __restrict__ KV)
{
    int i = blockIdx.x * 256 + threadIdx.x;
    if (i < KV_ELEMS) KV[i] = 0.f;
}

// ---------------------------------------------------------------------------
// FAVOR kv state via MFMA. Per (b,h): KV[32x33] = kp^T[32xL] @ [V|1][Lx33].
// ---------------------------------------------------------------------------
__global__ __launch_bounds__(256) void kv_mfma(
    const bf16_t* __restrict__ QKV, float* __restrict__ KV)
{
    __shared__ __align__(16) char smem[24576];
    bf16_t (*kp)[36] = (bf16_t(*)[36])smem;                 // 128x36x2 = 9216 B
    bf16_t (*vv)[52] = (bf16_t(*)[52])(smem + 9216);        // 128x52x2 = 13312 B
    float (*red)[6][64][4] = (float(*)[6][64][4])smem;      // 24576 B (aliases)

    const int bh = blockIdx.x;
    const int b = bh >> 3, h = bh & 7;
    const size_t rowbase = (size_t)b * LSEQ + blockIdx.y * 512;
    const int tid = threadIdx.x;
    const int wave = tid >> 6, lane = tid & 63;
    const int quad = lane >> 4, mr = lane & 15;

    for (int e = tid; e < 128 * 20; e += 256) {
        const int l = e / 20, c = 32 + (e % 20);
        vv[l][c] = (c == 32) ? (bf16_t)0x3F80 : (bf16_t)0;
    }

    float4v acc[2][3];
#pragma unroll
    for (int i = 0; i < 2; i++)
#pragma unroll
        for (int t = 0; t < 3; t++) acc[i][t] = (float4v)(0.f);

    for (int pass = 0; pass < 4; pass++) {
        __syncthreads();
        const size_t lp = rowbase + pass * 128;
#pragma unroll
        for (int it = 0; it < 4; it++) {
            const int e = tid + it * 256;
            const int l = e >> 3, c0 = (e & 7) * 4;
            const bf16_t* src = QKV + (lp + l) * 768 + 256 + h * 32 + c0;
            ushort4 kq = *(const ushort4*)src;
            ushort4 vq = *(const ushort4*)(src + 256);
            ushort4 ko;
            ko.x = f2b(fmaxf(b2f(kq.x), 0.f) + KEPS_F);
            ko.y = f2b(fmaxf(b2f(kq.y), 0.f) + KEPS_F);
            ko.z = f2b(fmaxf(b2f(kq.z), 0.f) + KEPS_F);
            ko.w = f2b(fmaxf(b2f(kq.w), 0.f) + KEPS_F);
            *(ushort4*)&kp[l][c0] = ko;
            *(ushort4*)&vv[l][c0] = vq;
        }
        __syncthreads();

        const int lw = wave * 32 + quad * 8;
        short8 a[2], bb[3];
#pragma unroll
        for (int i = 0; i < 2; i++)
#pragma unroll
            for (int j = 0; j < 8; j++)
                a[i][j] = (short)kp[lw + j][i * 16 + mr];
#pragma unroll
        for (int t = 0; t < 3; t++)
#pragma unroll
            for (int j = 0; j < 8; j++)
                bb[t][j] = (short)vv[lw + j][t * 16 + mr];
#pragma unroll
        for (int i = 0; i < 2; i++)
#pragma unroll
            for (int t = 0; t < 3; t++)
                acc[i][t] = __builtin_amdgcn_mfma_f32_16x16x32_bf16(
                    a[i], bb[t], acc[i][t], 0, 0, 0);
    }

    __syncthreads();
#pragma unroll
    for (int i = 0; i < 2; i++)
#pragma unroll
        for (int t = 0; t < 3; t++)
#pragma unroll
            for (int r = 0; r < 4; r++)
                red[wave][i * 3 + t][lane][r] = acc[i][t][r];
    __syncthreads();

    float* dst = KV + (size_t)bh * (32 * 33);
    for (int e = tid; e < 6 * 64 * 4; e += 256) {
        const int t = e >> 8, li = (e >> 2) & 63, r = e & 3;
        const float s = red[0][t][li][r] + red[1][t][li][r]
                      + red[2][t][li][r] + red[3][t][li][r];
        const int i = t / 3, j = t % 3;
        const int m = i * 16 + (li >> 4) * 4 + r;
        const int d = j * 16 + (li & 15);
        if (d < 33) atomicAdd(&dst[m * 33 + d], s);
    }
}

// ---------------------------------------------------------------------------
// Head (fp32 out): out[0:4096] = x[:,0,:] ; out[4096:4608] = x@qpW + qpb
// ---------------------------------------------------------------------------
__global__ __launch_bounds__(256) void head_kernel(
    const bf16_t* __restrict__ X, const float* __restrict__ qpW,
    const float* __restrict__ qpb, float* __restrict__ out)
{
    const int b = blockIdx.x, j = threadIdx.x;
    __shared__ float xr[HIDD];
    float v = b2f(X[((size_t)b * LSEQ) * HIDD + j]);
    xr[j] = v;
    out[b * HIDD + j] = v;
    __syncthreads();
    if (j < 32) {
        float acc = qpb[j];
        for (int d = 0; d < HIDD; d++)
            acc = fmaf(xr[d], qpW[d * 32 + j], acc);
        out[NB * HIDD + b * 32 + j] = acc;
    }
}

// ---------------------------------------------------------------------------
extern "C" void kernel_launch(void* const* d_in, const int* in_sizes, int n_in,
                              void* d_out, int out_size, void* d_ws, size_t ws_size,
                              hipStream_t stream)
{
    const float* hidden = (const float*)d_in[0];
    const float* ins    = (const float*)d_in[1];
    const int*   resets = (const int*)d_in[2];
    const float* embW   = (const float*)d_in[3];
    const float* embb   = (const float*)d_in[4];
    const float* Wq = (const float*)d_in[5];
    const float* bq = (const float*)d_in[6];
    const float* Wk = (const float*)d_in[7];
    const float* bk = (const float*)d_in[8];
    const float* Wv = (const float*)d_in[9];
    const float* bv = (const float*)d_in[10];
    const float* Wo = (const float*)d_in[11];
    const float* bo = (const float*)d_in[12];
    const float* ln1s = (const float*)d_in[13];
    const float* ln1b = (const float*)d_in[14];
    const float* W1 = (const float*)d_in[15];
    const float* b1 = (const float*)d_in[16];
    const float* W2 = (const float*)d_in[17];
    const float* b2 = (const float*)d_in[18];
    const float* ln2s = (const float*)d_in[19];
    const float* ln2b = (const float*)d_in[20];
    const float* qpW = (const float*)d_in[21];
    const float* qpb = (const float*)d_in[22];

    // ---- workspace (~195 MB < 256 MiB) ----
    const size_t ACT_SZ = (size_t)MROWS * HIDD;            // 16.78M elems
    bf16_t* X    = (bf16_t*)d_ws;                          // 33.5 MB
    bf16_t* QKV  = X + ACT_SZ;                             // 65536x768 = 100.7 MB
    bf16_t* H1   = QKV;                                    // alias: 65536x1024 (134 MB span)
    bf16_t* Ain  = QKV;                                    // alias (pre-layer only)
    bf16_t* Afav = QKV + (size_t)MROWS * 768;              // spare tail of H1 span, 33.5 MB
    float*  KV   = (float*)(QKV + (size_t)MROWS * FFD);    // after H1 span
    float*  bqkv = KV + KV_ELEMS;                          // 4x768 f32
    bf16_t* WqkvT = (bf16_t*)(bqkv + NLAY * 768);          // [l][768][256]
    bf16_t* WoT   = WqkvT + (size_t)NLAY * 3 * HIDD * HIDD;
    bf16_t* W1T   = WoT + (size_t)NLAY * HIDD * HIDD;
    bf16_t* W2T   = W1T + (size_t)NLAY * HIDD * FFD;
    bf16_t* embWT = W2T + (size_t)NLAY * FFD * HIDD;

    const dim3 blk(256);
    const dim3 blk512(512);
    const size_t HH = (size_t)HIDD * HIDD;

    conv_transpose_kernel<<<dim3(8, 8, NLAY), blk, 0, stream>>>(Wq, WqkvT,          HIDD, HIDD, HH, 3 * HH);
    conv_transpose_kernel<<<dim3(8, 8, NLAY), blk, 0, stream>>>(Wk, WqkvT + HH,     HIDD, HIDD, HH, 3 * HH);
    conv_transpose_kernel<<<dim3(8, 8, NLAY), blk, 0, stream>>>(Wv, WqkvT + 2 * HH, HIDD, HIDD, HH, 3 * HH);
    conv_transpose_kernel<<<dim3(8, 8, NLAY), blk, 0, stream>>>(Wo, WoT, HIDD, HIDD, HH, HH);
    conv_transpose_kernel<<<dim3(32, 8, NLAY), blk, 0, stream>>>(W1, W1T, HIDD, FFD, (size_t)HIDD * FFD, (size_t)HIDD * FFD);
    conv_transpose_kernel<<<dim3(8, 32, NLAY), blk, 0, stream>>>(W2, W2T, FFD, HIDD, (size_t)HIDD * FFD, (size_t)HIDD * FFD);
    conv_transpose_kernel<<<dim3(8, 4, 1), blk, 0, stream>>>(embW, embWT, 128, HIDD, 0, 0);
    concat_bias_kernel<<<NLAY, blk, 0, stream>>>(bq, bk, bv, bqkv);

    prep_a_kernel<<<MROWS / 2, blk, 0, stream>>>(ins, Ain);
    // embed: M=65536, N=256, K=128 -> 256 blocks (Nn=1), KT=4
    gemm_pipe2<0><<<dim3(256), blk512, 0, stream>>>(Ain, embWT, embb, X, MROWS, HIDD, 128, 128, HIDD);
    fix_row0_kernel<<<NB, blk, 0, stream>>>(hidden, resets, X);

    for (int l = 0; l < NLAY; l++) {
        // fused QKV projection: X[M][256] @ Wqkv[256][768] -> QKV[M][768]
        gemm_pipe2<0><<<dim3(256 * 3), blk512, 0, stream>>>(X, WqkvT + (size_t)l * 3 * HH,
                                                            bqkv + l * 768, QKV, MROWS, 768, HIDD, HIDD, 768);

        zero_kv<<<(KV_ELEMS + 255) / 256, blk, 0, stream>>>(KV);
        kv_mfma<<<dim3(NB * NHEAD, 8), blk, 0, stream>>>(QKV, KV);

        // favor A-gen -> Afav (standalone, latency-tolerant)
        favor_a_kernel<<<dim3(MROWS / 128), blk512, 0, stream>>>(QKV, KV, Afav);

        // Wo + residual-doubling + LN1 via pipelined GEMM v2 (K=256) -> X
        gemm_pipe2_ln<<<dim3(256), blk512, 0, stream>>>(
            Afav, WoT + (size_t)l * HH, bo + l * HIDD,
            ln1s + l * HIDD, ln1b + l * HIDD, X, HIDD, HIDD);

        // FF1 (pipelined v2): X @ W1 -> H1 (over dead QKV region + spare)
        gemm_pipe2<1><<<dim3(256 * 4), blk512, 0, stream>>>(X, W1T + (size_t)l * HIDD * FFD,
                                                            b1 + l * FFD, H1, MROWS, FFD, HIDD, HIDD, FFD);
        // FF2 + residual-doubling + LN2 fused -> X (pipelined v2, K=1024)
        gemm_pipe2_ln<<<dim3(256), blk512, 0, stream>>>(
            H1, W2T + (size_t)l * FFD * HIDD, b2 + l * HIDD,
            ln2s + l * HIDD, ln2b + l * HIDD, X, FFD, FFD);
    }

    head_kernel<<<NB, blk, 0, stream>>>(X, qpW, qpb, (float*)d_out);
}

// Round 8
// 963.638 us; speedup vs baseline: 1.1130x; 1.1130x over previous
//
#include <hip/hip_runtime.h>

// ---------------------------------------------------------------------------
// TransformerAgent (Performer/FAVOR+ encoder), MI355X gfx950.
// Round 22: CONSOLIDATION — best-of-breed components from 8 structures:
//  - embed/QKV/FF1: r14's 2-barrier 128x256 gemm_mfma (proven fastest:
//    FF1 53.1us vs 59.3-66.4 for all pipelined variants; 60 VGPR, 48KB LDS,
//    2+ blocks/CU). r21's LDS-staged store epilogue REVERTED (8-way write
//    bank conflicts, 2.1M SQ_LDS_BANK_CONFLICT, no write-BW gain -> the
//    write path was never the limiter).
//  - Wo-LN/FF2: r19's gemm_pipe2_ln (256-row, 3-slot ring; never in top-5).
//  - favor: r18 split (favor_a standalone + Wo-LN as plain GEMM).
// B=16, L=4096(=1+4095), HID=256, NH=8, DH=32, FF=1024, NL=4, ACT=32
// ---------------------------------------------------------------------------

typedef unsigned short bf16_t;
typedef __attribute__((ext_vector_type(8))) short short8;
typedef __attribute__((ext_vector_type(4))) float float4v;

#define NB 16
#define LSEQ 4096
#define MROWS (NB * LSEQ)      // 65536
#define HIDD 256
#define NHEAD 8
#define DHEAD 32
#define FFD 1024
#define NLAY 4
#define KEPS_F 1e-3f
#define LNEPS_F 1e-6f
#define KV_ELEMS (NB * NHEAD * 32 * 33)   // 135168

__device__ __forceinline__ float b2f(bf16_t h) {
    return __uint_as_float(((unsigned int)h) << 16);
}
__device__ __forceinline__ bf16_t f2b(float f) {
    unsigned int u = __float_as_uint(f);
    u += 0x7fffu + ((u >> 16) & 1u);   // round-to-nearest-even
    return (bf16_t)(u >> 16);
}

// async global->LDS, 16B per lane
#define GLOAD_LDS16(g, l)                                                     \
    __builtin_amdgcn_global_load_lds(                                         \
        (const __attribute__((address_space(1))) void*)(g),                   \
        (__attribute__((address_space(3))) void*)(l), 16, 0, 0)

// raw barrier + counted waits (used by the pipe2_ln core)
#define SBAR() __builtin_amdgcn_s_barrier()
#define WAITV(n)                                                              \
    do {                                                                      \
        asm volatile("s_waitcnt vmcnt(" #n ")" ::: "memory");                 \
        __builtin_amdgcn_sched_barrier(0);                                    \
    } while (0)

// pipe2_ln fragment read: (row R, k-chunk quad) of a [256]x32 panel in
// pair-row-XOR-swizzled chunk order.
#define FRAG16(L, R)                                                          \
    (*(const short8*)&(L)[((((R) >> 1) * 8) +                                  \
        (((((R) & 1) << 2) | quad) ^ (((R) >> 1) & 7))) * 8])

// ---------------------------------------------------------------------------
// Convert+transpose: in[z*ils + R][C] f32 -> out[z*ols + C][R] bf16.
// ---------------------------------------------------------------------------
__global__ __launch_bounds__(256) void conv_transpose_kernel(
    const float* __restrict__ in, bf16_t* __restrict__ out, int R, int C,
    size_t ils, size_t ols)
{
    __shared__ float tile[32][33];
    const size_t ib = (size_t)blockIdx.z * ils;
    const size_t ob = (size_t)blockIdx.z * ols;
    const int r0 = blockIdx.y * 32, c0 = blockIdx.x * 32;
    const int tx = threadIdx.x & 31, ty = threadIdx.x >> 5;   // 32 x 8
#pragma unroll
    for (int rr = ty; rr < 32; rr += 8)
        tile[rr][tx] = in[ib + (size_t)(r0 + rr) * C + c0 + tx];
    __syncthreads();
#pragma unroll
    for (int rr = ty; rr < 32; rr += 8)
        out[ob + (size_t)(c0 + rr) * R + r0 + tx] = f2b(tile[tx][rr]);
}

// concat per-layer q/k/v biases into bqkv[l][768]
__global__ __launch_bounds__(256) void concat_bias_kernel(
    const float* __restrict__ bq, const float* __restrict__ bk,
    const float* __restrict__ bv, float* __restrict__ bqkv)
{
    const int l = blockIdx.x, j = threadIdx.x;
    bqkv[l * 768 + j]       = bq[l * 256 + j];
    bqkv[l * 768 + 256 + j] = bk[l * 256 + j];
    bqkv[l * 768 + 512 + j] = bv[l * 256 + j];
}

// ---------------------------------------------------------------------------
// Embed A-prep: Ain[b*4096+l][128] = (l==0) ? 0 : bf16(ins[b][l-1][:])
// ---------------------------------------------------------------------------
__global__ __launch_bounds__(256) void prep_a_kernel(
    const float* __restrict__ ins, bf16_t* __restrict__ Ain)
{
    const int row = blockIdx.x * 2 + (threadIdx.x >> 7);
    const int j = threadIdx.x & 127;
    const int b = row >> 12, l = row & (LSEQ - 1);
    bf16_t v = 0;
    if (l != 0) v = f2b(ins[((size_t)b * 4095 + (l - 1)) * 128 + j]);
    Ain[(size_t)row * 128 + j] = v;
}

// X[b,0,:] = resets ? 0 : hidden
__global__ __launch_bounds__(256) void fix_row0_kernel(
    const float* __restrict__ hidden, const int* __restrict__ resets,
    bf16_t* __restrict__ X)
{
    const int b = blockIdx.x, j = threadIdx.x;
    float v = resets[b] ? 0.f : hidden[b * HIDD + j];
    X[((size_t)b * LSEQ) * HIDD + j] = f2b(v);
}

// ---------------------------------------------------------------------------
// MFMA GEMM (r14, proven fastest): C = act(A @ W + bias); WT[N][K].
// 512 thr = 8 waves, block 128x256, wave 64x64 (2m x 4n). XOR-swizzled LDS.
// 1-D grid with XCD-aware decode. Requires M/128 % 8 == 0.
// ---------------------------------------------------------------------------
template <int MODE>
__global__ __launch_bounds__(512) void gemm_mfma(
    const bf16_t* __restrict__ A, const bf16_t* __restrict__ WT,
    const float* __restrict__ bias, bf16_t* __restrict__ C,
    int M, int N, int K, int lda, int ldc)
{
    __shared__ __align__(16) bf16_t As[128 * 64];   // 16 KB
    __shared__ __align__(16) bf16_t Bs[256 * 64];   // 32 KB
    const int tid = threadIdx.x;
    const int wave = tid >> 6, lane = tid & 63;

    // XCD-aware decode (identity when N==256)
    const int Nn = N >> 8;
    const int id = blockIdx.x;
    const int s = id >> 3;
    const int bm = ((id & 7) + ((s / Nn) << 3)) * 128;
    const int bn = (s % Nn) * 256;

    const int quad = lane >> 4, mr = lane & 15;
    const int mxor = mr & 7;
    const int wm0 = (wave & 1) * 64;       // m-half
    const int wn0 = (wave >> 1) * 64;      // n-quarter

    float4v acc[4][4];
#pragma unroll
    for (int i = 0; i < 4; i++)
#pragma unroll
        for (int j = 0; j < 4; j++) acc[i][j] = (float4v)(0.f);

    for (int k0 = 0; k0 < K; k0 += 64) {
#pragma unroll
        for (int it = 0; it < 2; it++) {            // A: 1024 chunks
            const int c = it * 512 + tid;
            const int r = c >> 3;
            const int kofs = ((c & 7) ^ (r & 7)) * 8;
            GLOAD_LDS16(A + (size_t)(bm + r) * lda + k0 + kofs, &As[c * 8]);
        }
#pragma unroll
        for (int it = 0; it < 4; it++) {            // B: 2048 chunks
            const int c = it * 512 + tid;
            const int r = c >> 3;
            const int kofs = ((c & 7) ^ (r & 7)) * 8;
            GLOAD_LDS16(WT + (size_t)(bn + r) * K + k0 + kofs, &Bs[c * 8]);
        }
        __syncthreads();
#pragma unroll
        for (int kk = 0; kk < 8; kk += 4) {
            short8 a[4], b[4];
#pragma unroll
            for (int i = 0; i < 4; i++)
                a[i] = *(const short8*)&As[((wm0 + i * 16 + mr) * 8 + ((quad + kk) ^ mxor)) * 8];
#pragma unroll
            for (int j = 0; j < 4; j++)
                b[j] = *(const short8*)&Bs[((wn0 + j * 16 + mr) * 8 + ((quad + kk) ^ mxor)) * 8];
#pragma unroll
            for (int i = 0; i < 4; i++)
#pragma unroll
                for (int j = 0; j < 4; j++)
                    acc[i][j] = __builtin_amdgcn_mfma_f32_16x16x32_bf16(
                        a[i], b[j], acc[i][j], 0, 0, 0);
        }
        __syncthreads();
    }

    float bcol[4];
#pragma unroll
    for (int j = 0; j < 4; j++) bcol[j] = bias[bn + wn0 + j * 16 + mr];
#pragma unroll
    for (int i = 0; i < 4; i++) {
#pragma unroll
        for (int r = 0; r < 4; r++) {
            const int grow = bm + wm0 + i * 16 + quad * 4 + r;
            bf16_t* crow = C + (size_t)grow * ldc + bn + wn0 + mr;
#pragma unroll
            for (int j = 0; j < 4; j++) {
                float v = acc[i][j][r] + bcol[j];
                if (MODE == 1) v = fmaxf(v, 0.f);
                crow[j * 16] = f2b(v);
            }
        }
    }
}

// ---------------------------------------------------------------------------
// Pipelined v2 core + fused LayerNorm epilogue (r19, proven for LN GEMMs):
// out = LN(2*(A@W + bias)) * sc + bi.  N=256 fixed, 256 rows/block.
// Used for Wo+LN1 (K=256) and FF2+LN2 (K=1024).
// ---------------------------------------------------------------------------
__global__ __launch_bounds__(512, 2) void gemm_pipe2_ln(
    const bf16_t* __restrict__ A, const bf16_t* __restrict__ WT,
    const float* __restrict__ bias, const float* __restrict__ sc,
    const float* __restrict__ bi, bf16_t* __restrict__ out,
    int K, int lda)
{
    __shared__ __align__(16) bf16_t As[3][256 * 32];   // 48 KB
    __shared__ __align__(16) bf16_t Bs[3][256 * 32];   // 48 KB
    __shared__ float red[8][128][2];                   // 8 KB
    __shared__ float fin[256][2];                      // 2 KB

    const int tid = threadIdx.x;
    const int wave = tid >> 6, lane = tid & 63;
    const int quad = lane >> 4, mr = lane & 15;
    const int bm = blockIdx.x << 8;                    // *256

    const int wm = (wave & 1) << 7;
    const int wn = (wave >> 1) << 6;

    const int KT = K >> 5;

    float bcol[4], scv[4], biv[4];
#pragma unroll
    for (int j = 0; j < 4; ++j) {
        bcol[j] = bias[wn + j * 16 + mr];
        scv[j]  = sc[wn + j * 16 + mr];
        biv[j]  = bi[wn + j * 16 + mr];
    }
    asm volatile("s_waitcnt vmcnt(0)" ::: "memory");
    __builtin_amdgcn_sched_barrier(0);

    auto stageA = [&](int t) {
        const int k0 = t << 5;
        bf16_t* L = &As[t % 3][0];
#pragma unroll
        for (int it = 0; it < 2; ++it) {
            const int c = it * 512 + tid;
            const int r = c >> 2;
            const int up = ((((r & 1) << 2) | (c & 3)) ^ ((r >> 1) & 7));
            const int grow = ((r >> 1) << 1) | (up >> 2);
            GLOAD_LDS16(A + (size_t)(bm + grow) * lda + k0 + ((up & 3) << 3),
                        L + c * 8);
        }
    };
    auto stageB = [&](int t) {
        const int k0 = t << 5;
        bf16_t* L = &Bs[t % 3][0];
#pragma unroll
        for (int it = 0; it < 2; ++it) {
            const int c = it * 512 + tid;
            const int r = c >> 2;
            const int up = ((((r & 1) << 2) | (c & 3)) ^ ((r >> 1) & 7));
            const int grow = ((r >> 1) << 1) | (up >> 2);
            GLOAD_LDS16(WT + (size_t)grow * K + k0 + ((up & 3) << 3),
                        L + c * 8);
        }
    };

    float4v acc[8][4];
#pragma unroll
    for (int i = 0; i < 8; i++)
#pragma unroll
        for (int j = 0; j < 4; j++) acc[i][j] = (float4v)(0.f);

    const int P = KT < 2 ? KT : 2;
    for (int tt = 0; tt < P; ++tt) { stageA(tt); stageB(tt); }

    for (int t = 0; t < KT; ++t) {
        if (t < KT - 1) { WAITV(4); } else { WAITV(0); }
        SBAR();
        __builtin_amdgcn_sched_barrier(0);
        const bf16_t* LA = &As[t % 3][0];
        const bf16_t* LB = &Bs[t % 3][0];
        short8 a0[4], a1[4], b[4];
#pragma unroll
        for (int j = 0; j < 4; ++j) b[j]  = FRAG16(LB, wn + j * 16 + mr);
#pragma unroll
        for (int i = 0; i < 4; ++i) a0[i] = FRAG16(LA, wm + i * 16 + mr);
#pragma unroll
        for (int i = 0; i < 4; ++i) a1[i] = FRAG16(LA, wm + 64 + i * 16 + mr);
        if (t + 2 < KT) { stageA(t + 2); stageB(t + 2); }
        __builtin_amdgcn_s_setprio(1);
        __builtin_amdgcn_sched_barrier(0);
#pragma unroll
        for (int i = 0; i < 4; ++i)
#pragma unroll
            for (int j = 0; j < 4; ++j)
                acc[i][j] = __builtin_amdgcn_mfma_f32_16x16x32_bf16(
                    a0[i], b[j], acc[i][j], 0, 0, 0);
#pragma unroll
        for (int i = 0; i < 4; ++i)
#pragma unroll
            for (int j = 0; j < 4; ++j)
                acc[4 + i][j] = __builtin_amdgcn_mfma_f32_16x16x32_bf16(
                    a1[i], b[j], acc[4 + i][j], 0, 0, 0);
        __builtin_amdgcn_sched_barrier(0);
        __builtin_amdgcn_s_setprio(0);
    }

#pragma unroll
    for (int i = 0; i < 8; ++i) {
#pragma unroll
        for (int r = 0; r < 4; ++r) {
            float ss = 0.f, s2 = 0.f;
#pragma unroll
            for (int j = 0; j < 4; ++j) {
                const float v = 2.0f * (acc[i][j][r] + bcol[j]);
                ss += v; s2 += v * v;
            }
#pragma unroll
            for (int off = 1; off < 16; off <<= 1) {
                ss += __shfl_xor(ss, off, 64);
                s2 += __shfl_xor(s2, off, 64);
            }
            if (mr == 0) {
                const int rl = i * 16 + quad * 4 + r;
                red[wave][rl][0] = ss;
                red[wave][rl][1] = s2;
            }
        }
    }
    __syncthreads();
    {
        const int R = tid >> 1, p = tid & 1;
        const int mh = R >> 7, rl = R & 127;
        fin[R][p] = red[mh][rl][p] + red[mh + 2][rl][p]
                  + red[mh + 4][rl][p] + red[mh + 6][rl][p];
    }
    __syncthreads();

#pragma unroll
    for (int i = 0; i < 8; ++i) {
#pragma unroll
        for (int r = 0; r < 4; ++r) {
            const int R = wm + i * 16 + quad * 4 + r;
            const float mean = fin[R][0] * (1.0f / 256.0f);
            const float var  = fin[R][1] * (1.0f / 256.0f) - mean * mean;
            const float rs = rsqrtf(var + LNEPS_F);
            bf16_t* crow = out + (size_t)(bm + R) * 256 + wn + mr;
#pragma unroll
            for (int j = 0; j < 4; ++j) {
                const float v = 2.0f * (acc[i][j][r] + bcol[j]);
                crow[j * 16] = f2b((v - mean) * rs * scv[j] + biv[j]);
            }
        }
    }
}

// ---------------------------------------------------------------------------
// FAVOR A-gen (standalone, proven): Afav = (qp @ kv) / (qp @ kps).
// ---------------------------------------------------------------------------
__global__ __launch_bounds__(512) void favor_a_kernel(
    const bf16_t* __restrict__ QKV, const float* __restrict__ KV,
    bf16_t* __restrict__ Afav)
{
    __shared__ __align__(16) bf16_t kvT[NHEAD * 34 * 36];   // 19.1 KB

    const int tid = threadIdx.x;
    const int wave = tid >> 6, lane = tid & 63;
    const int bm = blockIdx.x * 128;
    const int b = bm >> 12;
    const int quad = lane >> 4, mr = lane & 15;

    for (int e = tid; e < NHEAD * 34 * 32; e += 512) {
        const int h = e / (34 * 32);
        const int rem = e - h * (34 * 32);
        const int d = rem >> 5, m = rem & 31;
        bf16_t v = 0;
        if (d < 33) v = f2b(KV[((size_t)(b * NHEAD + h)) * (32 * 33) + m * 33 + d]);
        kvT[(h * 34 + d) * 36 + m] = v;
    }
    __syncthreads();

    const int Rrow = bm + wave * 16 + mr;
    const size_t abase = (size_t)(bm + wave * 16) * 256;

    short8 araw[NHEAD];
#pragma unroll
    for (int h = 0; h < NHEAD; ++h)
        araw[h] = *(const short8*)(QKV + (size_t)Rrow * 768 + h * 32 + quad * 8);

#pragma unroll
    for (int h = 0; h < NHEAD; ++h) {
        short8 a;
#pragma unroll
        for (int j = 0; j < 8; j++)
            a[j] = (short)f2b(fmaxf(b2f((bf16_t)araw[h][j]), 0.f) + KEPS_F);
        short8 bf0 = *(const short8*)&kvT[(h * 34 + mr) * 36 + quad * 8];
        short8 bf1 = *(const short8*)&kvT[(h * 34 + 16 + mr) * 36 + quad * 8];
        short8 bden;
#pragma unroll
        for (int j = 0; j < 8; j++) bden[j] = 0;
        if (mr == 0)
            bden = *(const short8*)&kvT[(h * 34 + 32) * 36 + quad * 8];
        float4v c0 = __builtin_amdgcn_mfma_f32_16x16x32_bf16(a, bf0, (float4v)(0.f), 0, 0, 0);
        float4v c1 = __builtin_amdgcn_mfma_f32_16x16x32_bf16(a, bf1, (float4v)(0.f), 0, 0, 0);
        float4v c2 = __builtin_amdgcn_mfma_f32_16x16x32_bf16(a, bden, (float4v)(0.f), 0, 0, 0);
#pragma unroll
        for (int r = 0; r < 4; r++) {
            const float den = __shfl(c2[r], quad << 4);
            const float rinv = 1.0f / den;
            const int rl = quad * 4 + r;
            Afav[abase + (size_t)rl * 256 + h * 32 + mr]      = f2b(c0[r] * rinv);
            Afav[abase + (size_t)rl * 256 + h * 32 + 16 + mr] = f2b(c1[r] * rinv);
        }
    }
}

// ---------------------------------------------------------------------------
// Zero the KV accumulator
// ---------------------------------------------------------------------------
__global__ __launch_bounds__(256) void zero_kv(float* __restrict__ KV)
{
    int i = blockIdx.x * 256 + threadIdx.x;
    if (i < KV_ELEMS) KV[i] = 0.f;
}

// ---------------------------------------------------------------------------
// FAVOR kv state via MFMA. Per (b,h): KV[32x33] = kp^T[32xL] @ [V|1][Lx33].
// ---------------------------------------------------------------------------
__global__ __launch_bounds__(256) void kv_mfma(
    const bf16_t* __restrict__ QKV, float* __restrict__ KV)
{
    __shared__ __align__(16) char smem[24576];
    bf16_t (*kp)[36] = (bf16_t(*)[36])smem;                 // 128x36x2 = 9216 B
    bf16_t (*vv)[52] = (bf16_t(*)[52])(smem + 9216);        // 128x52x2 = 13312 B
    float (*red)[6][64][4] = (float(*)[6][64][4])smem;      // 24576 B (aliases)

    const int bh = blockIdx.x;
    const int b = bh >> 3, h = bh & 7;
    const size_t rowbase = (size_t)b * LSEQ + blockIdx.y * 512;
    const int tid = threadIdx.x;
    const int wave = tid >> 6, lane = tid & 63;
    const int quad = lane >> 4, mr = lane & 15;

    for (int e = tid; e < 128 * 20; e += 256) {
        const int l = e / 20, c = 32 + (e % 20);
        vv[l][c] = (c == 32) ? (bf16_t)0x3F80 : (bf16_t)0;
    }

    float4v acc[2][3];
#pragma unroll
    for (int i = 0; i < 2; i++)
#pragma unroll
        for (int t = 0; t < 3; t++) acc[i][t] = (float4v)(0.f);

    for (int pass = 0; pass < 4; pass++) {
        __syncthreads();
        const size_t lp = rowbase + pass * 128;
#pragma unroll
        for (int it = 0; it < 4; it++) {
            const int e = tid + it * 256;
            const int l = e >> 3, c0 = (e & 7) * 4;
            const bf16_t* src = QKV + (lp + l) * 768 + 256 + h * 32 + c0;
            ushort4 kq = *(const ushort4*)src;
            ushort4 vq = *(const ushort4*)(src + 256);
            ushort4 ko;
            ko.x = f2b(fmaxf(b2f(kq.x), 0.f) + KEPS_F);
            ko.y = f2b(fmaxf(b2f(kq.y), 0.f) + KEPS_F);
            ko.z = f2b(fmaxf(b2f(kq.z), 0.f) + KEPS_F);
            ko.w = f2b(fmaxf(b2f(kq.w), 0.f) + KEPS_F);
            *(ushort4*)&kp[l][c0] = ko;
            *(ushort4*)&vv[l][c0] = vq;
        }
        __syncthreads();

        const int lw = wave * 32 + quad * 8;
        short8 a[2], bb[3];
#pragma unroll
        for (int i = 0; i < 2; i++)
#pragma unroll
            for (int j = 0; j < 8; j++)
                a[i][j] = (short)kp[lw + j][i * 16 + mr];
#pragma unroll
        for (int t = 0; t < 3; t++)
#pragma unroll
            for (int j = 0; j < 8; j++)
                bb[t][j] = (short)vv[lw + j][t * 16 + mr];
#pragma unroll
        for (int i = 0; i < 2; i++)
#pragma unroll
            for (int t = 0; t < 3; t++)
                acc[i][t] = __builtin_amdgcn_mfma_f32_16x16x32_bf16(
                    a[i], bb[t], acc[i][t], 0, 0, 0);
    }

    __syncthreads();
#pragma unroll
    for (int i = 0; i < 2; i++)
#pragma unroll
        for (int t = 0; t < 3; t++)
#pragma unroll
            for (int r = 0; r < 4; r++)
                red[wave][i * 3 + t][lane][r] = acc[i][t][r];
    __syncthreads();

    float* dst = KV + (size_t)bh * (32 * 33);
    for (int e = tid; e < 6 * 64 * 4; e += 256) {
        const int t = e >> 8, li = (e >> 2) & 63, r = e & 3;
        const float s = red[0][t][li][r] + red[1][t][li][r]
                      + red[2][t][li][r] + red[3][t][li][r];
        const int i = t / 3, j = t % 3;
        const int m = i * 16 + (li >> 4) * 4 + r;
        const int d = j * 16 + (li & 15);
        if (d < 33) atomicAdd(&dst[m * 33 + d], s);
    }
}

// ---------------------------------------------------------------------------
// Head (fp32 out): out[0:4096] = x[:,0,:] ; out[4096:4608] = x@qpW + qpb
// ---------------------------------------------------------------------------
__global__ __launch_bounds__(256) void head_kernel(
    const bf16_t* __restrict__ X, const float* __restrict__ qpW,
    const float* __restrict__ qpb, float* __restrict__ out)
{
    const int b = blockIdx.x, j = threadIdx.x;
    __shared__ float xr[HIDD];
    float v = b2f(X[((size_t)b * LSEQ) * HIDD + j]);
    xr[j] = v;
    out[b * HIDD + j] = v;
    __syncthreads();
    if (j < 32) {
        float acc = qpb[j];
        for (int d = 0; d < HIDD; d++)
            acc = fmaf(xr[d], qpW[d * 32 + j], acc);
        out[NB * HIDD + b * 32 + j] = acc;
    }
}

// ---------------------------------------------------------------------------
extern "C" void kernel_launch(void* const* d_in, const int* in_sizes, int n_in,
                              void* d_out, int out_size, void* d_ws, size_t ws_size,
                              hipStream_t stream)
{
    const float* hidden = (const float*)d_in[0];
    const float* ins    = (const float*)d_in[1];
    const int*   resets = (const int*)d_in[2];
    const float* embW   = (const float*)d_in[3];
    const float* embb   = (const float*)d_in[4];
    const float* Wq = (const float*)d_in[5];
    const float* bq = (const float*)d_in[6];
    const float* Wk = (const float*)d_in[7];
    const float* bk = (const float*)d_in[8];
    const float* Wv = (const float*)d_in[9];
    const float* bv = (const float*)d_in[10];
    const float* Wo = (const float*)d_in[11];
    const float* bo = (const float*)d_in[12];
    const float* ln1s = (const float*)d_in[13];
    const float* ln1b = (const float*)d_in[14];
    const float* W1 = (const float*)d_in[15];
    const float* b1 = (const float*)d_in[16];
    const float* W2 = (const float*)d_in[17];
    const float* b2 = (const float*)d_in[18];
    const float* ln2s = (const float*)d_in[19];
    const float* ln2b = (const float*)d_in[20];
    const float* qpW = (const float*)d_in[21];
    const float* qpb = (const float*)d_in[22];

    // ---- workspace (~195 MB < 256 MiB) ----
    const size_t ACT_SZ = (size_t)MROWS * HIDD;            // 16.78M elems
    bf16_t* X    = (bf16_t*)d_ws;                          // 33.5 MB
    bf16_t* QKV  = X + ACT_SZ;                             // 65536x768 = 100.7 MB
    bf16_t* H1   = QKV;                                    // alias: 65536x1024 (134 MB span)
    bf16_t* Ain  = QKV;                                    // alias (pre-layer only)
    bf16_t* Afav = QKV + (size_t)MROWS * 768;              // spare tail of H1 span, 33.5 MB
    float*  KV   = (float*)(QKV + (size_t)MROWS * FFD);    // after H1 span
    float*  bqkv = KV + KV_ELEMS;                          // 4x768 f32
    bf16_t* WqkvT = (bf16_t*)(bqkv + NLAY * 768);          // [l][768][256]
    bf16_t* WoT   = WqkvT + (size_t)NLAY * 3 * HIDD * HIDD;
    bf16_t* W1T   = WoT + (size_t)NLAY * HIDD * HIDD;
    bf16_t* W2T   = W1T + (size_t)NLAY * HIDD * FFD;
    bf16_t* embWT = W2T + (size_t)NLAY * FFD * HIDD;

    const dim3 blk(256);
    const dim3 blk512(512);
    const size_t HH = (size_t)HIDD * HIDD;

    conv_transpose_kernel<<<dim3(8, 8, NLAY), blk, 0, stream>>>(Wq, WqkvT,          HIDD, HIDD, HH, 3 * HH);
    conv_transpose_kernel<<<dim3(8, 8, NLAY), blk, 0, stream>>>(Wk, WqkvT + HH,     HIDD, HIDD, HH, 3 * HH);
    conv_transpose_kernel<<<dim3(8, 8, NLAY), blk, 0, stream>>>(Wv, WqkvT + 2 * HH, HIDD, HIDD, HH, 3 * HH);
    conv_transpose_kernel<<<dim3(8, 8, NLAY), blk, 0, stream>>>(Wo, WoT, HIDD, HIDD, HH, HH);
    conv_transpose_kernel<<<dim3(32, 8, NLAY), blk, 0, stream>>>(W1, W1T, HIDD, FFD, (size_t)HIDD * FFD, (size_t)HIDD * FFD);
    conv_transpose_kernel<<<dim3(8, 32, NLAY), blk, 0, stream>>>(W2, W2T, FFD, HIDD, (size_t)HIDD * FFD, (size_t)HIDD * FFD);
    conv_transpose_kernel<<<dim3(8, 4, 1), blk, 0, stream>>>(embW, embWT, 128, HIDD, 0, 0);
    concat_bias_kernel<<<NLAY, blk, 0, stream>>>(bq, bk, bv, bqkv);

    prep_a_kernel<<<MROWS / 2, blk, 0, stream>>>(ins, Ain);
    // embed: M=65536, N=256, K=128 -> 512 blocks (Nn=1)
    gemm_mfma<0><<<dim3(512), blk512, 0, stream>>>(Ain, embWT, embb, X, MROWS, HIDD, 128, 128, HIDD);
    fix_row0_kernel<<<NB, blk, 0, stream>>>(hidden, resets, X);

    for (int l = 0; l < NLAY; l++) {
        // fused QKV projection: X[M][256] @ Wqkv[256][768] -> QKV[M][768]
        gemm_mfma<0><<<dim3(512 * 3), blk512, 0, stream>>>(X, WqkvT + (size_t)l * 3 * HH,
                                                           bqkv + l * 768, QKV, MROWS, 768, HIDD, HIDD, 768);

        zero_kv<<<(KV_ELEMS + 255) / 256, blk, 0, stream>>>(KV);
        kv_mfma<<<dim3(NB * NHEAD, 8), blk, 0, stream>>>(QKV, KV);

        // favor A-gen -> Afav (standalone, latency-tolerant)
        favor_a_kernel<<<dim3(MROWS / 128), blk512, 0, stream>>>(QKV, KV, Afav);

        // Wo + residual-doubling + LN1 via pipelined GEMM v2 (K=256) -> X
        gemm_pipe2_ln<<<dim3(256), blk512, 0, stream>>>(
            Afav, WoT + (size_t)l * HH, bo + l * HIDD,
            ln1s + l * HIDD, ln1b + l * HIDD, X, HIDD, HIDD);

        // FF1 (r14 core): X @ W1 -> H1 (over dead QKV region + spare)
        gemm_mfma<1><<<dim3(512 * 4), blk512, 0, stream>>>(X, W1T + (size_t)l * HIDD * FFD,
                                                           b1 + l * FFD, H1, MROWS, FFD, HIDD, HIDD, FFD);
        // FF2 + residual-doubling + LN2 fused -> X (pipelined v2, K=1024)
        gemm_pipe2_ln<<<dim3(256), blk512, 0, stream>>>(
            H1, W2T + (size_t)l * FFD * HIDD, b2 + l * HIDD,
            ln2s + l * HIDD, ln2b + l * HIDD, X, FFD, FFD);
    }

    head_kernel<<<NB, blk, 0, stream>>>(X, qpW, qpb, (float*)d_out);
}